// Round 2
// baseline (2163.790 us; speedup 1.0000x reference)
//
#include <hip/hip_runtime.h>
#include <math.h>

#define T_TOK 8192
#define NEXP  256
#define HD    7168

// ---- Router GEMM: tile 128x128, TM=TN=8, BK=16, 256 threads, split-K via d_ws partials ----
#define BM 128
#define BN 128
#define BK 16
#define LDA (BM + 4)
#define LDB (BN + 4)
#define PLANE ((size_t)T_TOK * NEXP)

__global__ __launch_bounds__(256, 2) void router_gemm(
    const float* __restrict__ X, const float* __restrict__ W,
    float* __restrict__ partial, int S) {
  __shared__ float As[2][BK][LDA];
  __shared__ float Bs[2][BK][LDB];

  const int tid = threadIdx.x;
  const int id  = blockIdx.x;
  // id = mb + 64*nb + 128*sb : blocks sharing an A-panel differ by multiples of 64
  // -> same (id % 8) XCD -> A re-read hits that XCD's L2.
  const int mb  = id & 63;
  const int nb  = (id >> 6) & 1;
  const int sb  = id >> 7;

  const int row0 = mb * BM, col0 = nb * BN;
  const int klen  = HD / S;
  const int kbeg  = sb * klen;
  const int nstep = klen / BK;

  // compute-lane layout: within a wave 8x8 (tx8,ty8) -> LDS frag reads are
  // 8 distinct 32B addresses = 2-way bank aliasing (free).
  const int lane = tid & 63, wv = tid >> 6;
  const int tx = (lane & 7) + (wv & 1) * 8;    // 0..15
  const int ty = (lane >> 3) + (wv >> 1) * 8;  // 0..15

  // staging layout: thread -> (row sm, float4 col sk); transposed LDS writes are 2-way.
  const int sm = tid >> 2;  // 0..63
  const int sk = tid & 3;   // 0..3

  const float* Ap = X + (size_t)(row0 + sm) * HD + kbeg + sk * 4;
  const float* Bp = W + (size_t)(col0 + sm) * HD + kbeg + sk * 4;

  float acc[8][8];
#pragma unroll
  for (int i = 0; i < 8; ++i)
#pragma unroll
    for (int j = 0; j < 8; ++j) acc[i][j] = 0.f;

  float4 ga[2], gb[2];
  // prologue: load + stage step 0 into buf 0
  ga[0] = *(const float4*)(Ap);
  ga[1] = *(const float4*)(Ap + (size_t)64 * HD);
  gb[0] = *(const float4*)(Bp);
  gb[1] = *(const float4*)(Bp + (size_t)64 * HD);
#pragma unroll
  for (int p = 0; p < 2; ++p) {
    const float* fa = (const float*)&ga[p];
    const float* fb = (const float*)&gb[p];
#pragma unroll
    for (int j = 0; j < 4; ++j) {
      As[0][sk * 4 + j][sm + p * 64] = fa[j];
      Bs[0][sk * 4 + j][sm + p * 64] = fb[j];
    }
  }

  for (int t = 0; t < nstep; ++t) {
    const int buf = t & 1;
    __syncthreads();  // buf ready for all waves; buf^1 free (no reader since last barrier)

    const bool more = (t + 1 < nstep);
    if (more) {
      const float* Ap2 = Ap + (size_t)(t + 1) * BK;
      const float* Bp2 = Bp + (size_t)(t + 1) * BK;
      ga[0] = *(const float4*)(Ap2);
      ga[1] = *(const float4*)(Ap2 + (size_t)64 * HD);
      gb[0] = *(const float4*)(Bp2);
      gb[1] = *(const float4*)(Bp2 + (size_t)64 * HD);
    }

#pragma unroll
    for (int kk = 0; kk < BK; ++kk) {
      const float4 a0 = *(const float4*)&As[buf][kk][ty * 8];
      const float4 a1 = *(const float4*)&As[buf][kk][ty * 8 + 4];
      const float4 b0 = *(const float4*)&Bs[buf][kk][tx * 8];
      const float4 b1 = *(const float4*)&Bs[buf][kk][tx * 8 + 4];
      const float a[8] = {a0.x, a0.y, a0.z, a0.w, a1.x, a1.y, a1.z, a1.w};
      const float b[8] = {b0.x, b0.y, b0.z, b0.w, b1.x, b1.y, b1.z, b1.w};
#pragma unroll
      for (int i = 0; i < 8; ++i)
#pragma unroll
        for (int j = 0; j < 8; ++j) acc[i][j] = fmaf(a[i], b[j], acc[i][j]);
    }

    if (more) {
      const int nbuf = buf ^ 1;
#pragma unroll
      for (int p = 0; p < 2; ++p) {
        const float* fa = (const float*)&ga[p];
        const float* fb = (const float*)&gb[p];
#pragma unroll
        for (int j = 0; j < 4; ++j) {
          As[nbuf][sk * 4 + j][sm + p * 64] = fa[j];
          Bs[nbuf][sk * 4 + j][sm + p * 64] = fb[j];
        }
      }
    }
  }

  float* out0 = partial + (size_t)sb * PLANE + (size_t)(row0 + ty * 8) * NEXP + col0 + tx * 8;
#pragma unroll
  for (int i = 0; i < 8; ++i) {
    float4 v0, v1;
    v0.x = acc[i][0]; v0.y = acc[i][1]; v0.z = acc[i][2]; v0.w = acc[i][3];
    v1.x = acc[i][4]; v1.y = acc[i][5]; v1.z = acc[i][6]; v1.w = acc[i][7];
    *(float4*)(out0 + (size_t)i * NEXP)     = v0;
    *(float4*)(out0 + (size_t)i * NEXP + 4) = v1;
  }
}

// ---------------- Gating: one wave per token (sums S split-K partials) ----------------
__global__ __launch_bounds__(256) void gate_kernel(const float* __restrict__ logits,
                                                   const float* __restrict__ bias,
                                                   float* __restrict__ out_w,
                                                   float* __restrict__ out_e, int S) {
    const int wave = threadIdx.x >> 6;
    const int lane = threadIdx.x & 63;
    const int t = blockIdx.x * 4 + wave;
    if (t >= T_TOK) return;

    float l4[4] = {0.f, 0.f, 0.f, 0.f};
    for (int s = 0; s < S; ++s) {  // fixed order -> deterministic rounding
        const float4 v = *(const float4*)(&logits[(size_t)s * PLANE + (size_t)t * NEXP + lane * 4]);
        l4[0] += v.x; l4[1] += v.y; l4[2] += v.z; l4[3] += v.w;
    }
    const float4 bv = *(const float4*)(&bias[lane * 4]);

    float s4[4], c[4];
#pragma unroll
    for (int j = 0; j < 4; ++j) s4[j] = 1.f / (1.f + expf(-l4[j]));
    c[0] = s4[0] + bv.x;
    c[1] = s4[1] + bv.y;
    c[2] = s4[2] + bv.z;
    c[3] = s4[3] + bv.w;

    // group score: sum of top-2 within group of 32 (8 lanes/group)
    float a = fmaxf(c[0], c[1]), b = fminf(c[0], c[1]);
    float d = fmaxf(c[2], c[3]), e = fminf(c[2], c[3]);
    float m1 = fmaxf(a, d);
    float m2 = fmaxf(fminf(a, d), fmaxf(b, e));
#pragma unroll
    for (int off = 1; off < 8; off <<= 1) {
        const float o1 = __shfl_xor(m1, off);
        const float o2 = __shfl_xor(m2, off);
        const float n1 = fmaxf(m1, o1);
        const float n2 = fmaxf(fminf(m1, o1), fmaxf(m2, o2));
        m1 = n1; m2 = n2;
    }
    const float gs = m1 + m2;
    const int   g  = lane >> 3;

    int rank = 0;
#pragma unroll
    for (int gg = 0; gg < 8; ++gg) {
        const float og = __shfl(gs, gg * 8);
        rank += (og > gs) || (og == gs && gg < g);
    }
    const bool gsel = rank < 4;

    float v[4];
#pragma unroll
    for (int j = 0; j < 4; ++j) v[j] = gsel ? c[j] : 0.0f;

    float selw = 0.f;
    int   seli = 0;
    float wsum = 0.f;

#pragma unroll
    for (int k = 0; k < 8; ++k) {
        float bvv = v[0]; int bi = lane * 4; float br = s4[0];
#pragma unroll
        for (int j = 1; j < 4; ++j) {
            if (v[j] > bvv) { bvv = v[j]; bi = lane * 4 + j; br = s4[j]; }
        }
#pragma unroll
        for (int off = 32; off > 0; off >>= 1) {
            const float ov = __shfl_xor(bvv, off);
            const int   oi = __shfl_xor(bi, off);
            const float orr = __shfl_xor(br, off);
            if (ov > bvv || (ov == bvv && oi < bi)) { bvv = ov; bi = oi; br = orr; }
        }
        if (lane == k) { selw = br; seli = bi; }
        wsum += br;
        const int rem = bi - lane * 4;
#pragma unroll
        for (int j = 0; j < 4; ++j)
            if (rem == j) v[j] = -INFINITY;
    }

    if (lane < 8) {
        const float w = selw / (wsum + 1e-20f) * 2.5f;
        out_w[(size_t)t * 8 + lane] = w;
        out_e[(size_t)t * 8 + lane] = (float)seli;
    }
}

extern "C" void kernel_launch(void* const* d_in, const int* in_sizes, int n_in,
                              void* d_out, int out_size, void* d_ws, size_t ws_size,
                              hipStream_t stream) {
    const float* X    = (const float*)d_in[0];
    const float* W    = (const float*)d_in[1];
    const float* bias = (const float*)d_in[2];
    float* out    = (float*)d_out;
    float* logits = (float*)d_ws;

    // split-K factor limited by workspace (8 MB per partial plane)
    int S = 1;
    if (ws_size >= (size_t)4 * PLANE * sizeof(float)) S = 4;
    else if (ws_size >= (size_t)2 * PLANE * sizeof(float)) S = 2;

    router_gemm<<<dim3(128 * S), 256, 0, stream>>>(X, W, logits, S);
    gate_kernel<<<T_TOK / 4, 256, 0, stream>>>(logits, bias, out, out + (size_t)T_TOK * 8, S);
}

// Round 3
// 131.019 us; speedup vs baseline: 16.5150x; 16.5150x over previous
//
#include <hip/hip_runtime.h>
#include <math.h>

#define T_TOK 8192
#define NEXP  256
#define HD    7168
#define PLANE ((size_t)T_TOK * NEXP)
#define WELEMS ((size_t)NEXP * HD)          // 1,835,008
#define SCALE 4096.0f
#define INV_S2 (1.0f / 16777216.0f)         // 2^-24, exact

typedef _Float16 h8 __attribute__((ext_vector_type(8)));
typedef _Float16 h4 __attribute__((ext_vector_type(4)));
typedef float    f4 __attribute__((ext_vector_type(4)));

// ---------------- W -> f16 hi/lo planes (scaled by 4096) ----------------
__global__ __launch_bounds__(256) void wconv(const float* __restrict__ W,
                                             _Float16* __restrict__ Wh,
                                             _Float16* __restrict__ Wl) {
  const size_t i = ((size_t)blockIdx.x * 256 + threadIdx.x) * 4;
  const float4 w = *(const float4*)(W + i);
  const float ws[4] = {w.x * SCALE, w.y * SCALE, w.z * SCALE, w.w * SCALE};
  h4 hv, lv;
#pragma unroll
  for (int j = 0; j < 4; ++j) {
    const _Float16 hh = (_Float16)ws[j];
    hv[j] = hh;
    lv[j] = (_Float16)(ws[j] - (float)hh);
  }
  *(h4*)(Wh + i) = hv;
  *(h4*)(Wl + i) = lv;
}

// ---------------- Router GEMM: 128x256 tile, f16 MFMA, 3-product split ----------------
#define BM 128
#define BN 256
#define BK 32
#define LDF 40   // halfs per LDS row (32 + 8 pad) -> 80 B, 16B-aligned rows

__global__ __launch_bounds__(512, 2) void router_gemm(
    const float* __restrict__ X, const _Float16* __restrict__ Wh,
    const _Float16* __restrict__ Wl, float* __restrict__ partial, int S) {
  __shared__ _Float16 As[2][2][BM][LDF];   // [dbuf][hi/lo][row][k] 40 KB
  __shared__ _Float16 Bs[2][2][BN][LDF];   // 80 KB

  const int tid = threadIdx.x;
  const int id  = blockIdx.x;              // id = mb*S + sb -> same-sb blocks share W K-slice in XCD L2
  const int sb  = id % S;
  const int mb  = id / S;

  const int row0  = mb * BM;
  const int klen  = HD / S;
  const int kbeg  = sb * klen;
  const int nstep = klen / BK;

  const int lane = tid & 63, wv = tid >> 6;
  const int wm = wv >> 2, wn = wv & 3;     // 2(M) x 4(N) waves, each 64x64
  const int fr = lane & 15, kg = lane >> 4;

  // staging map: thread -> (row sm, 8-half k-slot sk)
  const int sm = tid >> 2;                 // 0..127
  const int sk = tid & 3;                  // 0..3

  const float*    Ap = X  + (size_t)(row0 + sm) * HD + kbeg + sk * 8;
  const _Float16* Bh = Wh + (size_t)sm * HD + kbeg + sk * 8;
  const _Float16* Bl = Wl + (size_t)sm * HD + kbeg + sk * 8;

  f4 acc[4][4];
#pragma unroll
  for (int i = 0; i < 4; ++i)
#pragma unroll
    for (int j = 0; j < 4; ++j) acc[i][j] = (f4){0.f, 0.f, 0.f, 0.f};

  float4 ga0, ga1;
  h8 gbh0, gbh1, gbl0, gbl1;

#define LOADG(t)                                                        \
  {                                                                     \
    const size_t off = (size_t)(t) * BK;                                \
    ga0  = *(const float4*)(Ap + off);                                  \
    ga1  = *(const float4*)(Ap + off + 4);                              \
    gbh0 = *(const h8*)(Bh + off);                                      \
    gbh1 = *(const h8*)(Bh + off + (size_t)128 * HD);                   \
    gbl0 = *(const h8*)(Bl + off);                                      \
    gbl1 = *(const h8*)(Bl + off + (size_t)128 * HD);                   \
  }

#define STAGE(b)                                                        \
  {                                                                     \
    const float xs[8] = {ga0.x, ga0.y, ga0.z, ga0.w,                    \
                         ga1.x, ga1.y, ga1.z, ga1.w};                   \
    h8 hv, lv;                                                          \
    _Pragma("unroll")                                                   \
    for (int j = 0; j < 8; ++j) {                                       \
      const float v = xs[j] * SCALE;                                    \
      const _Float16 hh = (_Float16)v;                                  \
      hv[j] = hh;                                                       \
      lv[j] = (_Float16)(v - (float)hh);                                \
    }                                                                   \
    *(h8*)&As[b][0][sm][sk * 8] = hv;                                   \
    *(h8*)&As[b][1][sm][sk * 8] = lv;                                   \
    *(h8*)&Bs[b][0][sm][sk * 8] = gbh0;                                 \
    *(h8*)&Bs[b][0][sm + 128][sk * 8] = gbh1;                           \
    *(h8*)&Bs[b][1][sm][sk * 8] = gbl0;                                 \
    *(h8*)&Bs[b][1][sm + 128][sk * 8] = gbl1;                           \
  }

  LOADG(0);
  STAGE(0);

  for (int t = 0; t < nstep; ++t) {
    const int cur = t & 1;
    __syncthreads();   // buf[cur] staged for all; everyone done reading buf[cur^1]
    const bool more = (t + 1 < nstep);
    if (more) LOADG(t + 1);

    h8 ah[4], al[4];
#pragma unroll
    for (int mi = 0; mi < 4; ++mi) {
      const int r = wm * 64 + mi * 16 + fr;
      ah[mi] = *(const h8*)&As[cur][0][r][kg * 8];
      al[mi] = *(const h8*)&As[cur][1][r][kg * 8];
    }
#pragma unroll
    for (int ni = 0; ni < 4; ++ni) {
      const int c = wn * 64 + ni * 16 + fr;
      const h8 bh = *(const h8*)&Bs[cur][0][c][kg * 8];
      const h8 bl = *(const h8*)&Bs[cur][1][c][kg * 8];
#pragma unroll
      for (int mi = 0; mi < 4; ++mi) {
        acc[mi][ni] = __builtin_amdgcn_mfma_f32_16x16x32_f16(ah[mi], bh, acc[mi][ni], 0, 0, 0);
        acc[mi][ni] = __builtin_amdgcn_mfma_f32_16x16x32_f16(al[mi], bh, acc[mi][ni], 0, 0, 0);
        acc[mi][ni] = __builtin_amdgcn_mfma_f32_16x16x32_f16(ah[mi], bl, acc[mi][ni], 0, 0, 0);
      }
    }
    if (more) STAGE((t + 1) & 1);
  }

  // Epilogue: C/D layout col=lane&15, row=(lane>>4)*4+reg  [m89-verified]
  float* base = partial + (size_t)sb * PLANE;
  const int rb = (lane >> 4) * 4;
#pragma unroll
  for (int mi = 0; mi < 4; ++mi)
#pragma unroll
    for (int ni = 0; ni < 4; ++ni) {
      const int col = wn * 64 + ni * 16 + fr;
#pragma unroll
      for (int r = 0; r < 4; ++r) {
        const int row = row0 + wm * 64 + mi * 16 + rb + r;
        base[(size_t)row * NEXP + col] = acc[mi][ni][r];
      }
    }
}

// ---------------- Gating: one wave per token; sums S partial planes ----------------
__global__ __launch_bounds__(256) void gate_kernel(const float* __restrict__ logits,
                                                   const float* __restrict__ bias,
                                                   float* __restrict__ out_w,
                                                   float* __restrict__ out_e, int S) {
    const int wave = threadIdx.x >> 6;
    const int lane = threadIdx.x & 63;
    const int t = blockIdx.x * 4 + wave;
    if (t >= T_TOK) return;

    float l4[4] = {0.f, 0.f, 0.f, 0.f};
    for (int s = 0; s < S; ++s) {  // fixed order -> deterministic
        const float4 v = *(const float4*)(&logits[(size_t)s * PLANE + (size_t)t * NEXP + lane * 4]);
        l4[0] += v.x; l4[1] += v.y; l4[2] += v.z; l4[3] += v.w;
    }
    const float4 bv = *(const float4*)(&bias[lane * 4]);

    float s4[4], c[4];
#pragma unroll
    for (int j = 0; j < 4; ++j) s4[j] = 1.f / (1.f + expf(-l4[j] * INV_S2));
    c[0] = s4[0] + bv.x;
    c[1] = s4[1] + bv.y;
    c[2] = s4[2] + bv.z;
    c[3] = s4[3] + bv.w;

    float a = fmaxf(c[0], c[1]), b = fminf(c[0], c[1]);
    float d = fmaxf(c[2], c[3]), e = fminf(c[2], c[3]);
    float m1 = fmaxf(a, d);
    float m2 = fmaxf(fminf(a, d), fmaxf(b, e));
#pragma unroll
    for (int off = 1; off < 8; off <<= 1) {
        const float o1 = __shfl_xor(m1, off);
        const float o2 = __shfl_xor(m2, off);
        const float n1 = fmaxf(m1, o1);
        const float n2 = fmaxf(fminf(m1, o1), fmaxf(m2, o2));
        m1 = n1; m2 = n2;
    }
    const float gs = m1 + m2;
    const int   g  = lane >> 3;

    int rank = 0;
#pragma unroll
    for (int gg = 0; gg < 8; ++gg) {
        const float og = __shfl(gs, gg * 8);
        rank += (og > gs) || (og == gs && gg < g);
    }
    const bool gsel = rank < 4;

    float v[4];
#pragma unroll
    for (int j = 0; j < 4; ++j) v[j] = gsel ? c[j] : 0.0f;

    float selw = 0.f;
    int   seli = 0;
    float wsum = 0.f;

#pragma unroll
    for (int k = 0; k < 8; ++k) {
        float bvv = v[0]; int bi = lane * 4; float br = s4[0];
#pragma unroll
        for (int j = 1; j < 4; ++j) {
            if (v[j] > bvv) { bvv = v[j]; bi = lane * 4 + j; br = s4[j]; }
        }
#pragma unroll
        for (int off = 32; off > 0; off >>= 1) {
            const float ov = __shfl_xor(bvv, off);
            const int   oi = __shfl_xor(bi, off);
            const float orr = __shfl_xor(br, off);
            if (ov > bvv || (ov == bvv && oi < bi)) { bvv = ov; bi = oi; br = orr; }
        }
        if (lane == k) { selw = br; seli = bi; }
        wsum += br;
        const int rem = bi - lane * 4;
#pragma unroll
        for (int j = 0; j < 4; ++j)
            if (rem == j) v[j] = -INFINITY;
    }

    if (lane < 8) {
        const float w = selw / (wsum + 1e-20f) * 2.5f;
        out_w[(size_t)t * 8 + lane] = w;
        out_e[(size_t)t * 8 + lane] = (float)seli;
    }
}

extern "C" void kernel_launch(void* const* d_in, const int* in_sizes, int n_in,
                              void* d_out, int out_size, void* d_ws, size_t ws_size,
                              hipStream_t stream) {
    const float* X    = (const float*)d_in[0];
    const float* W    = (const float*)d_in[1];
    const float* bias = (const float*)d_in[2];
    float* out = (float*)d_out;

    _Float16* Whp = (_Float16*)d_ws;
    _Float16* Wlp = Whp + WELEMS;
    const size_t woff = 2 * WELEMS * sizeof(_Float16);   // 7,340,032 B
    float* partial = (float*)((char*)d_ws + woff);

    int S = 1;
    if (ws_size >= woff + 4 * PLANE * sizeof(float)) S = 4;
    else if (ws_size >= woff + 2 * PLANE * sizeof(float)) S = 2;

    wconv<<<dim3(WELEMS / (256 * 4)), 256, 0, stream>>>(W, Whp, Wlp);
    router_gemm<<<dim3((T_TOK / BM) * S), 512, 0, stream>>>(X, Whp, Wlp, partial, S);
    gate_kernel<<<dim3(T_TOK / 4), 256, 0, stream>>>(partial, bias, out, out + (size_t)T_TOK * 8, S);
}

// Round 4
// 129.541 us; speedup vs baseline: 16.7035x; 1.0114x over previous
//
#include <hip/hip_runtime.h>
#include <math.h>
#include <stdint.h>

#define T_TOK 8192
#define NEXP  256
#define HD    7168
#define PLANE ((size_t)T_TOK * NEXP)
#define SCALE 4096.0f
#define INV_S2 (1.0f / 16777216.0f)   // 2^-24
#define BM 128
#define BK 32                          // fp32 K-columns per step
#define NSTEP_TOT (HD / BK)            // 224
#define BIMG_STEP 32768                // bytes of B image per K-step (2 hl * 256 * 32 * 2B)

typedef _Float16 h8  __attribute__((ext_vector_type(8)));
typedef float f32x16 __attribute__((ext_vector_type(16)));
typedef __attribute__((address_space(3))) uint8_t       lds_t;
typedef __attribute__((address_space(1))) const uint8_t gbl_t;

// ---- W -> pre-swizzled f16 hi/lo LDS image (so GEMM stages B with linear global_load_lds) ----
// Image byte c*16 (chunk c within step t) == LDS offset: hl=c>>10, row=(c&1023)>>2, sp=c&3.
// Content: plane hl of W[row][t*32 + (sp ^ ((row>>1)&3))*8 .. +7] * SCALE.
__global__ __launch_bounds__(256) void wconv(const float* __restrict__ W,
                                             _Float16* __restrict__ img) {
  const int cc  = blockIdx.x * 256 + threadIdx.x;   // global chunk id
  const int t   = cc >> 11;                         // 2048 chunks / step
  const int c   = cc & 2047;
  const int hl  = c >> 10;
  const int rem = c & 1023;
  const int row = rem >> 2;
  const int sp  = rem & 3;
  const int sl  = sp ^ ((row >> 1) & 3);
  const int k   = t * BK + sl * 8;

  const float* src = W + (size_t)row * HD + k;
  const float4 v0 = *(const float4*)src;
  const float4 v1 = *(const float4*)(src + 4);
  const float xs[8] = {v0.x, v0.y, v0.z, v0.w, v1.x, v1.y, v1.z, v1.w};
  h8 out;
#pragma unroll
  for (int j = 0; j < 8; ++j) {
    const float v = xs[j] * SCALE;
    const _Float16 hh = (_Float16)v;
    out[j] = hl ? (_Float16)(v - (float)hh) : hh;
  }
  *(h8*)(img + (size_t)cc * 8) = out;
}

// ---- Router GEMM: BM=128 x BN=256(all experts), 32x32x16 f16 MFMA, 3-product hi/lo split ----
__global__ __launch_bounds__(512) void router_gemm(
    const float* __restrict__ X, const _Float16* __restrict__ img,
    float* __restrict__ partial, int S) {
  __shared__ __align__(1024) _Float16 As[2][2][BM][BK];    // 32 KB
  __shared__ __align__(1024) _Float16 Bs[2][2][NEXP][BK];  // 64 KB

  const int tid = threadIdx.x;
  const int id  = blockIdx.x;
  const int sb  = id % S;
  const int mb  = id / S;

  const int row0  = mb * BM;
  const int nstep = (HD / S) / BK;
  const int tbase = sb * nstep;

  const int lane = tid & 63, wv = tid >> 6;
  const int wm = wv >> 2, wn = wv & 3;       // wave tile 64(M) x 64(N)
  const int r31 = lane & 31, kg = lane >> 5; // MFMA 32x32: row/col = lane&31, k-group = lane>>5

  const int sm = tid >> 2;                   // staging row 0..127
  const int sk = tid & 3;                    // staging slot
  const int spA = sk ^ ((sm >> 1) & 3);      // swizzled slot for A writes

  const float* Ap = X + (size_t)(row0 + sm) * HD + tbase * BK + sk * 8;
  const uint8_t* imgB = (const uint8_t*)img + (size_t)tbase * BIMG_STEP + tid * 16;

  f32x16 acc[2][2];
#pragma unroll
  for (int i = 0; i < 2; ++i)
#pragma unroll
    for (int j = 0; j < 2; ++j) acc[i][j] = (f32x16)(0.f);

#define STAGE_B(t, b)                                                          \
  {                                                                            \
    const uint8_t* g = imgB + (size_t)(t) * BIMG_STEP;                         \
    uint8_t* l = (uint8_t*)&Bs[b][0][0][0] + tid * 16;                         \
    _Pragma("unroll")                                                          \
    for (int i = 0; i < 4; ++i)                                                \
      __builtin_amdgcn_global_load_lds((gbl_t*)(uintptr_t)(g + i * 8192),      \
                                       (lds_t*)(uintptr_t)(l + i * 8192),      \
                                       16, 0, 0);                              \
  }

  // prologue: stage step 0 into buf 0
  STAGE_B(0, 0);
  {
    const float4 a0 = *(const float4*)(Ap);
    const float4 a1 = *(const float4*)(Ap + 4);
    const float xs[8] = {a0.x, a0.y, a0.z, a0.w, a1.x, a1.y, a1.z, a1.w};
    h8 hv, lv;
#pragma unroll
    for (int j = 0; j < 8; ++j) {
      const float v = xs[j] * SCALE;
      const _Float16 hh = (_Float16)v;
      hv[j] = hh; lv[j] = (_Float16)(v - (float)hh);
    }
    *(h8*)&As[0][0][sm][spA * 8] = hv;
    *(h8*)&As[0][1][sm][spA * 8] = lv;
  }

  for (int t = 0; t < nstep; ++t) {
    const int cur = t & 1;
    __syncthreads();   // buf[cur] ready; buf[cur^1] free

    const bool more = (t + 1 < nstep);
    float4 a0, a1;
    if (more) {
      STAGE_B(t + 1, cur ^ 1);                       // async global->LDS
      a0 = *(const float4*)(Ap + (size_t)(t + 1) * BK);      // issue early (T14)
      a1 = *(const float4*)(Ap + (size_t)(t + 1) * BK + 4);
    }

#pragma unroll
    for (int ks = 0; ks < 2; ++ks) {
      h8 aH[2], aL[2], bH[2], bL[2];
#pragma unroll
      for (int mi = 0; mi < 2; ++mi) {
        const int row = wm * 64 + mi * 32 + r31;
        const int sp  = (ks * 2 + kg) ^ ((row >> 1) & 3);
        aH[mi] = *(const h8*)&As[cur][0][row][sp * 8];
        aL[mi] = *(const h8*)&As[cur][1][row][sp * 8];
      }
#pragma unroll
      for (int ni = 0; ni < 2; ++ni) {
        const int col = wn * 64 + ni * 32 + r31;
        const int sp  = (ks * 2 + kg) ^ ((col >> 1) & 3);
        bH[ni] = *(const h8*)&Bs[cur][0][col][sp * 8];
        bL[ni] = *(const h8*)&Bs[cur][1][col][sp * 8];
      }
#pragma unroll
      for (int mi = 0; mi < 2; ++mi)
#pragma unroll
        for (int ni = 0; ni < 2; ++ni) {
          acc[mi][ni] = __builtin_amdgcn_mfma_f32_32x32x16_f16(aH[mi], bH[ni], acc[mi][ni], 0, 0, 0);
          acc[mi][ni] = __builtin_amdgcn_mfma_f32_32x32x16_f16(aL[mi], bH[ni], acc[mi][ni], 0, 0, 0);
          acc[mi][ni] = __builtin_amdgcn_mfma_f32_32x32x16_f16(aH[mi], bL[ni], acc[mi][ni], 0, 0, 0);
        }
    }

    if (more) {  // convert + LDS-write late: HBM latency hidden under MFMA block
      const int nb = cur ^ 1;
      const float xs[8] = {a0.x, a0.y, a0.z, a0.w, a1.x, a1.y, a1.z, a1.w};
      h8 hv, lv;
#pragma unroll
      for (int j = 0; j < 8; ++j) {
        const float v = xs[j] * SCALE;
        const _Float16 hh = (_Float16)v;
        hv[j] = hh; lv[j] = (_Float16)(v - (float)hh);
      }
      *(h8*)&As[nb][0][sm][spA * 8] = hv;
      *(h8*)&As[nb][1][sm][spA * 8] = lv;
    }
  }

  // Epilogue. 32x32 C/D: col = lane&31, row = (reg&3) + 8*(reg>>2) + 4*(lane>>5)  [m74/m101]
  float* base = partial + (size_t)sb * PLANE;
#pragma unroll
  for (int mi = 0; mi < 2; ++mi)
#pragma unroll
    for (int ni = 0; ni < 2; ++ni) {
      const int col = wn * 64 + ni * 32 + r31;
#pragma unroll
      for (int reg = 0; reg < 16; ++reg) {
        const int rr  = (reg & 3) + 8 * (reg >> 2) + 4 * kg;
        const int row = row0 + wm * 64 + mi * 32 + rr;
        base[(size_t)row * NEXP + col] = acc[mi][ni][reg];
      }
    }
}

// ---------------- Gating: one wave per token; sums S partial planes ----------------
__global__ __launch_bounds__(256) void gate_kernel(const float* __restrict__ logits,
                                                   const float* __restrict__ bias,
                                                   float* __restrict__ out_w,
                                                   float* __restrict__ out_e, int S) {
    const int wave = threadIdx.x >> 6;
    const int lane = threadIdx.x & 63;
    const int t = blockIdx.x * 4 + wave;
    if (t >= T_TOK) return;

    float l4[4] = {0.f, 0.f, 0.f, 0.f};
    for (int s = 0; s < S; ++s) {  // fixed order -> deterministic
        const float4 v = *(const float4*)(&logits[(size_t)s * PLANE + (size_t)t * NEXP + lane * 4]);
        l4[0] += v.x; l4[1] += v.y; l4[2] += v.z; l4[3] += v.w;
    }
    const float4 bv = *(const float4*)(&bias[lane * 4]);

    float s4[4], c[4];
#pragma unroll
    for (int j = 0; j < 4; ++j) s4[j] = 1.f / (1.f + expf(-l4[j] * INV_S2));
    c[0] = s4[0] + bv.x;
    c[1] = s4[1] + bv.y;
    c[2] = s4[2] + bv.z;
    c[3] = s4[3] + bv.w;

    float a = fmaxf(c[0], c[1]), b = fminf(c[0], c[1]);
    float d = fmaxf(c[2], c[3]), e = fminf(c[2], c[3]);
    float m1 = fmaxf(a, d);
    float m2 = fmaxf(fminf(a, d), fmaxf(b, e));
#pragma unroll
    for (int off = 1; off < 8; off <<= 1) {
        const float o1 = __shfl_xor(m1, off);
        const float o2 = __shfl_xor(m2, off);
        const float n1 = fmaxf(m1, o1);
        const float n2 = fmaxf(fminf(m1, o1), fmaxf(m2, o2));
        m1 = n1; m2 = n2;
    }
    const float gs = m1 + m2;
    const int   g  = lane >> 3;

    int rank = 0;
#pragma unroll
    for (int gg = 0; gg < 8; ++gg) {
        const float og = __shfl(gs, gg * 8);
        rank += (og > gs) || (og == gs && gg < g);
    }
    const bool gsel = rank < 4;

    float v[4];
#pragma unroll
    for (int j = 0; j < 4; ++j) v[j] = gsel ? c[j] : 0.0f;

    float selw = 0.f;
    int   seli = 0;
    float wsum = 0.f;

#pragma unroll
    for (int k = 0; k < 8; ++k) {
        float bvv = v[0]; int bi = lane * 4; float br = s4[0];
#pragma unroll
        for (int j = 1; j < 4; ++j) {
            if (v[j] > bvv) { bvv = v[j]; bi = lane * 4 + j; br = s4[j]; }
        }
#pragma unroll
        for (int off = 32; off > 0; off >>= 1) {
            const float ov = __shfl_xor(bvv, off);
            const int   oi = __shfl_xor(bi, off);
            const float orr = __shfl_xor(br, off);
            if (ov > bvv || (ov == bvv && oi < bi)) { bvv = ov; bi = oi; br = orr; }
        }
        if (lane == k) { selw = br; seli = bi; }
        wsum += br;
        const int rem = bi - lane * 4;
#pragma unroll
        for (int j = 0; j < 4; ++j)
            if (rem == j) v[j] = -INFINITY;
    }

    if (lane < 8) {
        const float w = selw / (wsum + 1e-20f) * 2.5f;
        out_w[(size_t)t * 8 + lane] = w;
        out_e[(size_t)t * 8 + lane] = (float)seli;
    }
}

extern "C" void kernel_launch(void* const* d_in, const int* in_sizes, int n_in,
                              void* d_out, int out_size, void* d_ws, size_t ws_size,
                              hipStream_t stream) {
    const float* X    = (const float*)d_in[0];
    const float* W    = (const float*)d_in[1];
    const float* bias = (const float*)d_in[2];
    float* out = (float*)d_out;

    _Float16* img = (_Float16*)d_ws;
    const size_t woff = (size_t)NSTEP_TOT * BIMG_STEP;   // 7,340,032 B
    float* partial = (float*)((char*)d_ws + woff);

    int S = 1;
    if (ws_size >= woff + 4 * PLANE * sizeof(float)) S = 4;
    else if (ws_size >= woff + 2 * PLANE * sizeof(float)) S = 2;

    wconv<<<dim3(NSTEP_TOT * 2048 / 256), 256, 0, stream>>>(W, img);
    router_gemm<<<dim3((T_TOK / BM) * S), 512, 0, stream>>>(X, img, partial, S);
    gate_kernel<<<dim3(T_TOK / 4), 256, 0, stream>>>(partial, bias, out, out + (size_t)T_TOK * 8, S);
}